// Round 9
// baseline (158.875 us; speedup 1.0000x reference)
//
#include <hip/hip_runtime.h>
#include <hip/hip_bf16.h>

#define IMG_W 1024
#define IMG_H 1024
#define TH    4           // output rows per block: 4096 blocks = 2 rounds of
                          // 8 blocks/CU -> finished slots refill (load balance)
#define VX    4           // pixels per thread (float4)
#define NTHREADS 256      // 256*4 = 1024 = full row width

#define ALPHA_ 0.85f
#define BETA_  0.15f
// scale-invariant constants: 81*C1, 81*C2
#define K1_ (81.0f * (0.01f * 0.01f))
#define K2_ (81.0f * (0.03f * 0.03f))

// R5-proven row load: two coalesced float4 + 4 predicated edge dwords
// (L1-served; R6 showed shuffle-based edges cost MORE than these loads).
__device__ __forceinline__ void load_row(const float* __restrict__ Pr,
                                         const float* __restrict__ Tr,
                                         int x, float pv[6], float tv[6]) {
    const float4 p4 = *reinterpret_cast<const float4*>(Pr + x);
    const float4 t4 = *reinterpret_cast<const float4*>(Tr + x);
    pv[1] = p4.x; pv[2] = p4.y; pv[3] = p4.z; pv[4] = p4.w;
    tv[1] = t4.x; tv[2] = t4.y; tv[3] = t4.z; tv[4] = t4.w;
    pv[0] = (x > 0)          ? Pr[x - 1]  : 0.f;
    pv[5] = (x + VX < IMG_W) ? Pr[x + VX] : 0.f;
    tv[0] = (x > 0)          ? Tr[x - 1]  : 0.f;
    tv[5] = (x + VX < IMG_W) ? Tr[x + VX] : 0.f;
}

__device__ __forceinline__ void hsum(const float pv[6], const float tv[6],
                                     float cp[VX], float ct[VX],
                                     float cpp[VX], float ctt[VX], float cpt[VX]) {
#pragma unroll
    for (int j = 0; j < VX; ++j) {
        const float a = pv[j], b = pv[j + 1], c = pv[j + 2];
        const float u = tv[j], v = tv[j + 1], w = tv[j + 2];
        cp[j]  = a + b + c;
        ct[j]  = u + v + w;
        cpp[j] = fmaf(a, a, fmaf(b, b, c * c));
        ctt[j] = fmaf(u, u, fmaf(v, v, w * w));
        cpt[j] = fmaf(a, u, fmaf(b, v, c * w));
    }
}

// MODE=0: per-block partials to ws[2*bid]; MODE=1: atomics (small-ws fallback).
// Pressure lessons: no min-waves bound (R4 spill); row loop rolled (R3: small
// trip counts auto-unroll -> VGPR blowup). Body = R5's (best measured, 44 VGPR).
template <int MODE>
__global__ void __launch_bounds__(NTHREADS)
ssim_l1_kernel(const float* __restrict__ pred, const float* __restrict__ tgt,
               float* __restrict__ ws) {
    const int tid = threadIdx.x;
    const int x   = tid * VX;
    const int y0  = blockIdx.y * TH;
    const size_t base = (size_t)blockIdx.z * (size_t)(IMG_W * IMG_H);
    const float* __restrict__ P = pred + base;
    const float* __restrict__ T = tgt + base;

    float ssim_acc = 0.f, l1_acc = 0.f;

    // 2-row persistent state: AB = rowsum(y-1)+rowsum(y), B = rowsum(y)
    float ABp[VX], ABt[VX], ABpp[VX], ABtt[VX], ABpt[VX];
    float Bp[VX],  Bt[VX],  Bpp[VX],  Btt[VX],  Bpt[VX];
    float cp[VX], ct[VX], cpp[VX], ctt[VX], cpt[VX];
    float pv[6], tv[6];

    // --- prologue: row y0-1 (zeros if above image) -> AB ---
    if (y0 > 0) {
        load_row(P + (size_t)(y0 - 1) * IMG_W, T + (size_t)(y0 - 1) * IMG_W,
                 x, pv, tv);
        hsum(pv, tv, ABp, ABt, ABpp, ABtt, ABpt);
    } else {
#pragma unroll
        for (int j = 0; j < VX; ++j) {
            ABp[j] = 0.f; ABt[j] = 0.f; ABpp[j] = 0.f; ABtt[j] = 0.f; ABpt[j] = 0.f;
        }
    }
    // --- row y0: B; AB += B; L1(y0) ---
    {
        load_row(P + (size_t)y0 * IMG_W, T + (size_t)y0 * IMG_W, x, pv, tv);
        hsum(pv, tv, Bp, Bt, Bpp, Btt, Bpt);
        l1_acc += fabsf(pv[1] - tv[1]) + fabsf(pv[2] - tv[2])
                + fabsf(pv[3] - tv[3]) + fabsf(pv[4] - tv[4]);
#pragma unroll
        for (int j = 0; j < VX; ++j) {
            ABp[j] += Bp[j];  ABt[j] += Bt[j];
            ABpp[j] += Bpp[j]; ABtt[j] += Btt[j]; ABpt[j] += Bpt[j];
        }
    }

    // --- preload row y0+1 (always < IMG_H) ---
    load_row(P + (size_t)(y0 + 1) * IMG_W, T + (size_t)(y0 + 1) * IMG_W, x, pv, tv);

    const float inv9 = 1.0f / 9.0f; (void)inv9;
#pragma clang loop unroll(disable)
    for (int yo = y0; yo < y0 + TH; ++yo) {
        // consume preloaded row yo+1
        hsum(pv, tv, cp, ct, cpp, ctt, cpt);
        if (yo + 1 < y0 + TH) {
            l1_acc += fabsf(pv[1] - tv[1]) + fabsf(pv[2] - tv[2])
                    + fabsf(pv[3] - tv[3]) + fabsf(pv[4] - tv[4]);
        }
        // reissue loads for row yo+2 (overlaps SSIM math below)
        {
            const int r2 = yo + 2;
            if ((r2 <= y0 + TH) && (r2 < IMG_H)) {
                load_row(P + (size_t)r2 * IMG_W, T + (size_t)r2 * IMG_W, x, pv, tv);
            } else {
#pragma unroll
                for (int k = 0; k < 6; ++k) { pv[k] = 0.f; tv[k] = 0.f; }
            }
        }

#pragma unroll
        for (int j = 0; j < VX; ++j) {
            const float Sp  = ABp[j]  + cp[j];
            const float St  = ABt[j]  + ct[j];
            const float Spp = ABpp[j] + cpp[j];
            const float Stt = ABtt[j] + ctt[j];
            const float Spt = ABpt[j] + cpt[j];

            // roll: AB <- B + c ; B <- c
            ABp[j]  = Bp[j]  + cp[j];  Bp[j]  = cp[j];
            ABt[j]  = Bt[j]  + ct[j];  Bt[j]  = ct[j];
            ABpp[j] = Bpp[j] + cpp[j]; Bpp[j] = cpp[j];
            ABtt[j] = Btt[j] + ctt[j]; Btt[j] = ctt[j];
            ABpt[j] = Bpt[j] + cpt[j]; Bpt[j] = cpt[j];

            // scale-invariant SSIM (n,d scaled by 81^2; cancels in the ratio)
            const float SpSt = Sp * St;
            const float Sp2  = Sp * Sp;
            const float St2  = St * St;
            const float n1 = fmaf(2.0f, SpSt, K1_);
            const float n2 = fmaf(-2.0f, SpSt, fmaf(18.0f, Spt, K2_));
            const float d1 = (Sp2 + St2) + K1_;
            const float d2 = (fmaf(9.0f, Spp, K2_) + fmaf(9.0f, Stt, -Sp2)) - St2;
            const float ssim = (n1 * n2) * __builtin_amdgcn_rcpf(d1 * d2);
            float vcl = fmaf(-0.5f, ssim, 0.5f);
            vcl = fminf(fmaxf(vcl, 0.0f), 1.0f);
            ssim_acc += vcl;
        }
    }

    // --- reduction: wave shuffle -> LDS across 4 waves -> one write/block ---
    float s = ssim_acc, l = l1_acc;
#pragma unroll
    for (int off = 32; off > 0; off >>= 1) {
        s += __shfl_down(s, off, 64);
        l += __shfl_down(l, off, 64);
    }
    __shared__ float red_s[NTHREADS / 64];
    __shared__ float red_l[NTHREADS / 64];
    const int wid = tid >> 6, lane = tid & 63;
    if (lane == 0) { red_s[wid] = s; red_l[wid] = l; }
    __syncthreads();
    if (tid == 0) {
        float ss = 0.f, ll = 0.f;
#pragma unroll
        for (int w = 0; w < NTHREADS / 64; ++w) { ss += red_s[w]; ll += red_l[w]; }
        if (MODE == 0) {
            const int bid = blockIdx.z * gridDim.y + blockIdx.y;
            ws[2 * bid]     = ss;   // every slot written every call: no pre-zero
            ws[2 * bid + 1] = ll;
        } else {
            atomicAdd(&ws[0], ss);
            atomicAdd(&ws[1], ll);
        }
    }
}

__global__ void zero_ws_kernel(float* __restrict__ ws) {
    ws[0] = 0.f;
    ws[1] = 0.f;
}

__global__ void __launch_bounds__(256)
finalize_partials_kernel(const float* __restrict__ ws, float* __restrict__ out,
                         int nblocks, float inv_total) {
    const int tid = threadIdx.x;
    float s = 0.f, l = 0.f;
    for (int i = tid; i < nblocks; i += 256) {
        s += ws[2 * i];
        l += ws[2 * i + 1];
    }
#pragma unroll
    for (int off = 32; off > 0; off >>= 1) {
        s += __shfl_down(s, off, 64);
        l += __shfl_down(l, off, 64);
    }
    __shared__ float red_s[4], red_l[4];
    const int wid = tid >> 6, lane = tid & 63;
    if (lane == 0) { red_s[wid] = s; red_l[wid] = l; }
    __syncthreads();
    if (tid == 0) {
        float ss = red_s[0] + red_s[1] + red_s[2] + red_s[3];
        float ll = red_l[0] + red_l[1] + red_l[2] + red_l[3];
        out[0] = ALPHA_ * (ss * inv_total) + BETA_ * (ll * inv_total);
    }
}

__global__ void finalize_atomic_kernel(const float* __restrict__ ws,
                                       float* __restrict__ out, float inv_total) {
    out[0] = ALPHA_ * (ws[0] * inv_total) + BETA_ * (ws[1] * inv_total);
}

extern "C" void kernel_launch(void* const* d_in, const int* in_sizes, int n_in,
                              void* d_out, int out_size, void* d_ws, size_t ws_size,
                              hipStream_t stream) {
    const float* pred = (const float*)d_in[0];
    const float* tgt  = (const float*)d_in[1];
    float* ws = (float*)d_ws;

    const int total = in_sizes[0];                 // 16 * 1024 * 1024
    const int nimg  = total / (IMG_W * IMG_H);     // 16
    const int nblk  = nimg * (IMG_H / TH);         // 4096
    const float inv_total = 1.0f / (float)total;

    dim3 grid(1, IMG_H / TH, nimg);

    if (ws_size >= (size_t)(2 * nblk) * sizeof(float)) {
        ssim_l1_kernel<0><<<grid, NTHREADS, 0, stream>>>(pred, tgt, ws);
        finalize_partials_kernel<<<1, 256, 0, stream>>>(ws, (float*)d_out,
                                                        nblk, inv_total);
    } else {
        zero_ws_kernel<<<1, 1, 0, stream>>>(ws);
        ssim_l1_kernel<1><<<grid, NTHREADS, 0, stream>>>(pred, tgt, ws);
        finalize_atomic_kernel<<<1, 1, 0, stream>>>(ws, (float*)d_out, inv_total);
    }
}

// Round 10
// 152.224 us; speedup vs baseline: 1.0437x; 1.0437x over previous
//
#include <hip/hip_runtime.h>
#include <hip/hip_bf16.h>

#define IMG_W 1024
#define IMG_H 1024
#define TH    8           // output rows per block: 2048 blocks (best measured)
#define VX    4           // pixels per thread (float4)
#define NTHREADS 256      // 256*4 = 1024 = full row width

#define ALPHA_ 0.85f
#define BETA_  0.15f
// scale-invariant constants: 81*C1, 81*C2
#define K1_ (81.0f * (0.01f * 0.01f))
#define K2_ (81.0f * (0.03f * 0.03f))

// R10: BRANCHLESS row load. Edge addresses are clamped in-bounds (always a
// legal speculative load), zero-pad applied via value select (v_cndmask).
// R5-R9's `(x>0) ? Pr[x-1] : 0.f` forced exec-mask branch regions around
// each edge load (compiler can't speculate possibly-OOB loads), splitting
// the 6-load batch into 5 waitcnt groups and defeating the dbuf pipeline.
__device__ __forceinline__ void load_row(const float* __restrict__ Pr,
                                         const float* __restrict__ Tr,
                                         int x, float pv[6], float tv[6]) {
    const int xl = (x > 0) ? (x - 1) : 0;                   // v_max-style clamp
    const int xr = (x + VX < IMG_W) ? (x + VX) : (IMG_W - 1);
    const float4 p4 = *reinterpret_cast<const float4*>(Pr + x);
    const float4 t4 = *reinterpret_cast<const float4*>(Tr + x);
    const float pl = Pr[xl], pr = Pr[xr];                   // unconditional
    const float tl = Tr[xl], tr = Tr[xr];                   // unconditional
    pv[1] = p4.x; pv[2] = p4.y; pv[3] = p4.z; pv[4] = p4.w;
    tv[1] = t4.x; tv[2] = t4.y; tv[3] = t4.z; tv[4] = t4.w;
    pv[0] = (x > 0)          ? pl : 0.f;    // cndmask on VALUE, not a branch
    pv[5] = (x + VX < IMG_W) ? pr : 0.f;
    tv[0] = (x > 0)          ? tl : 0.f;
    tv[5] = (x + VX < IMG_W) ? tr : 0.f;
}

__device__ __forceinline__ void zero_row(float pv[6], float tv[6]) {
#pragma unroll
    for (int k = 0; k < 6; ++k) { pv[k] = 0.f; tv[k] = 0.f; }
}

__device__ __forceinline__ void hsum(const float pv[6], const float tv[6],
                                     float cp[VX], float ct[VX],
                                     float cpp[VX], float ctt[VX], float cpt[VX]) {
#pragma unroll
    for (int j = 0; j < VX; ++j) {
        const float a = pv[j], b = pv[j + 1], c = pv[j + 2];
        const float u = tv[j], v = tv[j + 1], w = tv[j + 2];
        cp[j]  = a + b + c;
        ct[j]  = u + v + w;
        cpp[j] = fmaf(a, a, fmaf(b, b, c * c));
        ctt[j] = fmaf(u, u, fmaf(v, v, w * w));
        cpt[j] = fmaf(a, u, fmaf(b, v, c * w));
    }
}

__device__ __forceinline__ void ssim_step(const float cp[VX], const float ct[VX],
                                          const float cpp[VX], const float ctt[VX],
                                          const float cpt[VX],
                                          float ABp[VX], float ABt[VX],
                                          float ABpp[VX], float ABtt[VX], float ABpt[VX],
                                          float Bp[VX], float Bt[VX],
                                          float Bpp[VX], float Btt[VX], float Bpt[VX],
                                          float& ssim_acc) {
#pragma unroll
    for (int j = 0; j < VX; ++j) {
        const float Sp  = ABp[j]  + cp[j];
        const float St  = ABt[j]  + ct[j];
        const float Spp = ABpp[j] + cpp[j];
        const float Stt = ABtt[j] + ctt[j];
        const float Spt = ABpt[j] + cpt[j];

        ABp[j]  = Bp[j]  + cp[j];  Bp[j]  = cp[j];
        ABt[j]  = Bt[j]  + ct[j];  Bt[j]  = ct[j];
        ABpp[j] = Bpp[j] + cpp[j]; Bpp[j] = cpp[j];
        ABtt[j] = Btt[j] + ctt[j]; Btt[j] = ctt[j];
        ABpt[j] = Bpt[j] + cpt[j]; Bpt[j] = cpt[j];

        // scale-invariant SSIM (n,d scaled by 81^2; cancels in the ratio)
        const float SpSt = Sp * St;
        const float Sp2  = Sp * Sp;
        const float St2  = St * St;
        const float n1 = fmaf(2.0f, SpSt, K1_);
        const float n2 = fmaf(-2.0f, SpSt, fmaf(18.0f, Spt, K2_));
        const float d1 = (Sp2 + St2) + K1_;
        const float d2 = (fmaf(9.0f, Spp, K2_) + fmaf(9.0f, Stt, -Sp2)) - St2;
        const float ssim = (n1 * n2) * __builtin_amdgcn_rcpf(d1 * d2);
        float vcl = fmaf(-0.5f, ssim, 0.5f);
        vcl = fminf(fmaxf(vcl, 0.0f), 1.0f);
        ssim_acc += vcl;
    }
}

__device__ __forceinline__ float l1_row(const float pv[6], const float tv[6]) {
    return fabsf(pv[1] - tv[1]) + fabsf(pv[2] - tv[2])
         + fabsf(pv[3] - tv[3]) + fabsf(pv[4] - tv[4]);
}

// MODE=0: per-block partials to ws[2*bid]; MODE=1: atomics (small-ws fallback).
// Pressure lessons: no min-waves bound (R4 spill); outer loop rolled (R3).
// Depth-2 static double-buffer (R8 structure) + branchless loads (this round).
template <int MODE>
__global__ void __launch_bounds__(NTHREADS)
ssim_l1_kernel(const float* __restrict__ pred, const float* __restrict__ tgt,
               float* __restrict__ ws) {
    const int tid = threadIdx.x;
    const int x   = tid * VX;
    const int y0  = blockIdx.y * TH;
    const size_t base = (size_t)blockIdx.z * (size_t)(IMG_W * IMG_H);
    const float* __restrict__ P = pred + base;
    const float* __restrict__ T = tgt + base;

    float ssim_acc = 0.f, l1_acc = 0.f;

    float ABp[VX], ABt[VX], ABpp[VX], ABtt[VX], ABpt[VX];
    float Bp[VX],  Bt[VX],  Bpp[VX],  Btt[VX],  Bpt[VX];
    float cp[VX], ct[VX], cpp[VX], ctt[VX], cpt[VX];

    float pvA[6], tvA[6], pvB[6], tvB[6];   // static double-buffer

    // --- prologue: row y0-1 (zeros if above image) -> AB ---
    if (y0 > 0) {
        load_row(P + (size_t)(y0 - 1) * IMG_W, T + (size_t)(y0 - 1) * IMG_W,
                 x, pvA, tvA);
        hsum(pvA, tvA, ABp, ABt, ABpp, ABtt, ABpt);
    } else {
#pragma unroll
        for (int j = 0; j < VX; ++j) {
            ABp[j] = 0.f; ABt[j] = 0.f; ABpp[j] = 0.f; ABtt[j] = 0.f; ABpt[j] = 0.f;
        }
    }
    // --- row y0: B; AB += B; L1(y0) ---
    {
        load_row(P + (size_t)y0 * IMG_W, T + (size_t)y0 * IMG_W, x, pvA, tvA);
        hsum(pvA, tvA, Bp, Bt, Bpp, Btt, Bpt);
        l1_acc += l1_row(pvA, tvA);
#pragma unroll
        for (int j = 0; j < VX; ++j) {
            ABp[j] += Bp[j];  ABt[j] += Bt[j];
            ABpp[j] += Bpp[j]; ABtt[j] += Btt[j]; ABpt[j] += Bpt[j];
        }
    }

    // --- preload: row y0+1 -> bufA, row y0+2 -> bufB (both always < IMG_H) ---
    load_row(P + (size_t)(y0 + 1) * IMG_W, T + (size_t)(y0 + 1) * IMG_W, x, pvA, tvA);
    load_row(P + (size_t)(y0 + 2) * IMG_W, T + (size_t)(y0 + 2) * IMG_W, x, pvB, tvB);

    // --- main loop: 2 rows per iteration, static A/B buffer positions ---
#pragma clang loop unroll(disable)
    for (int i = 0; i < TH; i += 2) {
        // ===== A half: consume row y0+1+i (always owned for i <= TH-2) =====
        hsum(pvA, tvA, cp, ct, cpp, ctt, cpt);
        l1_acc += l1_row(pvA, tvA);
        {   // prefetch row y0+3+i into bufA (consumed 2 halves later)
            const int rA = y0 + 3 + i;
            if ((rA <= y0 + TH) && (rA < IMG_H)) {   // wave-uniform branch
                load_row(P + (size_t)rA * IMG_W, T + (size_t)rA * IMG_W, x, pvA, tvA);
            } else {
                zero_row(pvA, tvA);
            }
        }
        ssim_step(cp, ct, cpp, ctt, cpt,
                  ABp, ABt, ABpp, ABtt, ABpt,
                  Bp, Bt, Bpp, Btt, Bpt, ssim_acc);

        // ===== B half: consume row y0+2+i (owned iff i < TH-2) =====
        hsum(pvB, tvB, cp, ct, cpp, ctt, cpt);
        if (i < TH - 2) l1_acc += l1_row(pvB, tvB);
        {   // prefetch row y0+4+i into bufB
            const int rB = y0 + 4 + i;
            if ((rB <= y0 + TH) && (rB < IMG_H)) {   // wave-uniform branch
                load_row(P + (size_t)rB * IMG_W, T + (size_t)rB * IMG_W, x, pvB, tvB);
            } else {
                zero_row(pvB, tvB);
            }
        }
        ssim_step(cp, ct, cpp, ctt, cpt,
                  ABp, ABt, ABpp, ABtt, ABpt,
                  Bp, Bt, Bpp, Btt, Bpt, ssim_acc);
    }

    // --- reduction: wave shuffle -> LDS across 4 waves -> one write/block ---
    float s = ssim_acc, l = l1_acc;
#pragma unroll
    for (int off = 32; off > 0; off >>= 1) {
        s += __shfl_down(s, off, 64);
        l += __shfl_down(l, off, 64);
    }
    __shared__ float red_s[NTHREADS / 64];
    __shared__ float red_l[NTHREADS / 64];
    const int wid = tid >> 6, lane = tid & 63;
    if (lane == 0) { red_s[wid] = s; red_l[wid] = l; }
    __syncthreads();
    if (tid == 0) {
        float ss = 0.f, ll = 0.f;
#pragma unroll
        for (int w = 0; w < NTHREADS / 64; ++w) { ss += red_s[w]; ll += red_l[w]; }
        if (MODE == 0) {
            const int bid = blockIdx.z * gridDim.y + blockIdx.y;
            ws[2 * bid]     = ss;   // every slot written every call: no pre-zero
            ws[2 * bid + 1] = ll;
        } else {
            atomicAdd(&ws[0], ss);
            atomicAdd(&ws[1], ll);
        }
    }
}

__global__ void zero_ws_kernel(float* __restrict__ ws) {
    ws[0] = 0.f;
    ws[1] = 0.f;
}

__global__ void __launch_bounds__(256)
finalize_partials_kernel(const float* __restrict__ ws, float* __restrict__ out,
                         int nblocks, float inv_total) {
    const int tid = threadIdx.x;
    float s = 0.f, l = 0.f;
    for (int i = tid; i < nblocks; i += 256) {
        s += ws[2 * i];
        l += ws[2 * i + 1];
    }
#pragma unroll
    for (int off = 32; off > 0; off >>= 1) {
        s += __shfl_down(s, off, 64);
        l += __shfl_down(l, off, 64);
    }
    __shared__ float red_s[4], red_l[4];
    const int wid = tid >> 6, lane = tid & 63;
    if (lane == 0) { red_s[wid] = s; red_l[wid] = l; }
    __syncthreads();
    if (tid == 0) {
        float ss = red_s[0] + red_s[1] + red_s[2] + red_s[3];
        float ll = red_l[0] + red_l[1] + red_l[2] + red_l[3];
        out[0] = ALPHA_ * (ss * inv_total) + BETA_ * (ll * inv_total);
    }
}

__global__ void finalize_atomic_kernel(const float* __restrict__ ws,
                                       float* __restrict__ out, float inv_total) {
    out[0] = ALPHA_ * (ws[0] * inv_total) + BETA_ * (ws[1] * inv_total);
}

extern "C" void kernel_launch(void* const* d_in, const int* in_sizes, int n_in,
                              void* d_out, int out_size, void* d_ws, size_t ws_size,
                              hipStream_t stream) {
    const float* pred = (const float*)d_in[0];
    const float* tgt  = (const float*)d_in[1];
    float* ws = (float*)d_ws;

    const int total = in_sizes[0];                 // 16 * 1024 * 1024
    const int nimg  = total / (IMG_W * IMG_H);     // 16
    const int nblk  = nimg * (IMG_H / TH);         // 2048
    const float inv_total = 1.0f / (float)total;

    dim3 grid(1, IMG_H / TH, nimg);

    if (ws_size >= (size_t)(2 * nblk) * sizeof(float)) {
        ssim_l1_kernel<0><<<grid, NTHREADS, 0, stream>>>(pred, tgt, ws);
        finalize_partials_kernel<<<1, 256, 0, stream>>>(ws, (float*)d_out,
                                                        nblk, inv_total);
    } else {
        zero_ws_kernel<<<1, 1, 0, stream>>>(ws);
        ssim_l1_kernel<1><<<grid, NTHREADS, 0, stream>>>(pred, tgt, ws);
        finalize_atomic_kernel<<<1, 1, 0, stream>>>(ws, (float*)d_out, inv_total);
    }
}